// Round 1
// baseline (300.641 us; speedup 1.0000x reference)
//
#include <hip/hip_runtime.h>
#include <hip/hip_bf16.h>
#include <math.h>

// Problem constants
#define BB   16
#define CIN  16
#define HH   320
#define WW   320
#define OUTC 16
#define KK   4
#define HID  5
#define HWSZ (HH * WW)        // 102400
#define WMIX_STRIDE 12        // 9 taps padded to 12 for float4 LDS reads
#define WMIX_PER_B  (OUTC * CIN * WMIX_STRIDE)  // 3072

// ---------------------------------------------------------------------------
// Kernel 1: global average pool. One block per (b,c) plane.
// ---------------------------------------------------------------------------
__global__ __launch_bounds__(256)
void dg_pool_kernel(const float* __restrict__ x, float* __restrict__ pooled) {
    const int plane = blockIdx.x;              // b*CIN + c, 0..255
    const float4* p4 = (const float4*)(x + (size_t)plane * HWSZ);
    float s = 0.f;
    #pragma unroll 4
    for (int i = threadIdx.x; i < HWSZ / 4; i += 256) {
        float4 v = p4[i];
        s += (v.x + v.y) + (v.z + v.w);
    }
    // wave reduce (64 lanes)
    #pragma unroll
    for (int off = 32; off > 0; off >>= 1) s += __shfl_down(s, off, 64);
    __shared__ float red[4];
    if ((threadIdx.x & 63) == 0) red[threadIdx.x >> 6] = s;
    __syncthreads();
    if (threadIdx.x == 0) {
        float t = (red[0] + red[1]) + (red[2] + red[3]);
        pooled[plane] = t * (1.f / (float)HWSZ);
    }
}

// ---------------------------------------------------------------------------
// Kernel 2: attention MLP + scrambled softmax + expert mixing.
// One block per batch sample, 64 threads.
// wmix layout: [b][o*16+c][tap] with tap stride padded to 12.
// ---------------------------------------------------------------------------
__global__ __launch_bounds__(64)
void dg_mix_kernel(const float* __restrict__ pooled,
                   const float* __restrict__ w1,
                   const float* __restrict__ w2,
                   const float* __restrict__ b2,
                   const float* __restrict__ weight,
                   float* __restrict__ wmix) {
    const int b = blockIdx.x;
    const int tid = threadIdx.x;   // 0..63
    __shared__ float sm[64];       // attn logits
    __shared__ float coeff[64];    // scrambled softmax, flat (k*16+o) order

    // each thread redundantly computes hid[5], then its own attn[tid]
    float pb[CIN];
    #pragma unroll
    for (int c = 0; c < CIN; ++c) pb[c] = pooled[b * CIN + c];
    float hid[HID];
    #pragma unroll
    for (int h = 0; h < HID; ++h) {
        float a = 0.f;
        #pragma unroll
        for (int c = 0; c < CIN; ++c) a = fmaf(pb[c], w1[h * CIN + c], a);
        hid[h] = fmaxf(a, 0.f);
    }
    float a = b2[tid];
    #pragma unroll
    for (int h = 0; h < HID; ++h) a = fmaf(hid[h], w2[tid * HID + h], a);
    sm[tid] = a;
    __syncthreads();

    // softmax over the 4 experts for this thread's column oa = tid%16
    const int oa = tid & 15;
    float a0 = sm[oa], a1 = sm[16 + oa], a2 = sm[32 + oa], a3 = sm[48 + oa];
    float m = fmaxf(fmaxf(a0, a1), fmaxf(a2, a3));
    float denom = expf(a0 - m) + expf(a1 - m) + expf(a2 - m) + expf(a3 - m);
    coeff[tid] = expf(sm[tid] - m) / denom;   // = flat softmax at index tid
    __syncthreads();

    // wmix[b][oc][tap] = sum_k coeff[o*4+k] * weight[((oc)*9+tap)*4 + k]
    for (int idx = tid; idx < WMIX_PER_B; idx += 64) {
        const int oc  = idx / WMIX_STRIDE;
        const int tap = idx - oc * WMIX_STRIDE;
        float v = 0.f;
        if (tap < 9) {
            const int o = oc >> 4;
            const float* wp = weight + ((size_t)oc * 9 + tap) * KK;
            v = coeff[o * 4 + 0] * wp[0] + coeff[o * 4 + 1] * wp[1]
              + coeff[o * 4 + 2] * wp[2] + coeff[o * 4 + 3] * wp[3];
        }
        wmix[(size_t)b * WMIX_PER_B + idx] = v;
    }
}

// ---------------------------------------------------------------------------
// Kernel 3: the 3x3 conv. Each thread: 4 consecutive x-pixels x 16 out chans.
// Weights (per-b, 12.3 KB) staged in LDS, read as broadcast float4.
// Grid: (HW/1024, B). Block: 256.
// ---------------------------------------------------------------------------
__global__ __launch_bounds__(256, 4)
void dg_conv_kernel(const float* __restrict__ x,
                    const float* __restrict__ wmix,
                    float* __restrict__ out) {
    const int b = blockIdx.y;
    const int tid = threadIdx.x;

    __shared__ float wl[WMIX_PER_B];
    {
        const float4* wg = (const float4*)(wmix + (size_t)b * WMIX_PER_B);
        float4* wl4 = (float4*)wl;
        for (int i = tid; i < WMIX_PER_B / 4; i += 256) wl4[i] = wg[i];
    }
    __syncthreads();

    const int p0 = blockIdx.x * 1024 + tid * 4;   // base pixel (mult of 4)
    const int y  = p0 / WW;
    const int x0 = p0 - y * WW;
    const bool ym = (y > 0), yp = (y < HH - 1);
    const bool xm = (x0 > 0), xp = (x0 + 4 < WW);
    const float fm0 = ym ? 1.f : 0.f, fm2 = yp ? 1.f : 0.f;
    const int rom = ym ? -WW : 0, rop = yp ? WW : 0;

    const float* xb = x + (size_t)b * CIN * HWSZ + p0;

    float acc[64];
    #pragma unroll
    for (int i = 0; i < 64; ++i) acc[i] = 0.f;

    #pragma unroll 1
    for (int c = 0; c < CIN; ++c) {
        const float* xc = xb + c * HWSZ;
        float4 c0 = *(const float4*)(xc + rom);
        float4 c1 = *(const float4*)(xc);
        float4 c2 = *(const float4*)(xc + rop);
        float v0[6], v1[6], v2[6];
        v0[0] = (ym && xm) ? xc[-WW - 1] : 0.f;
        v0[5] = (ym && xp) ? xc[-WW + 4] : 0.f;
        v1[0] = xm ? xc[-1] : 0.f;
        v1[5] = xp ? xc[4] : 0.f;
        v2[0] = (yp && xm) ? xc[WW - 1] : 0.f;
        v2[5] = (yp && xp) ? xc[WW + 4] : 0.f;
        v0[1] = c0.x * fm0; v0[2] = c0.y * fm0; v0[3] = c0.z * fm0; v0[4] = c0.w * fm0;
        v1[1] = c1.x;       v1[2] = c1.y;       v1[3] = c1.z;       v1[4] = c1.w;
        v2[1] = c2.x * fm2; v2[2] = c2.y * fm2; v2[3] = c2.z * fm2; v2[4] = c2.w * fm2;

        #pragma unroll
        for (int o = 0; o < OUTC; ++o) {
            const float* w = &wl[(o * CIN + c) * WMIX_STRIDE];
            float4 wA = *(const float4*)(w);       // taps 0..3
            float4 wB = *(const float4*)(w + 4);   // taps 4..7
            float  wC = w[8];                      // tap 8
            #pragma unroll
            for (int j = 0; j < 4; ++j) {
                float s = acc[o * 4 + j];
                s = fmaf(v0[j + 0], wA.x, s);
                s = fmaf(v0[j + 1], wA.y, s);
                s = fmaf(v0[j + 2], wA.z, s);
                s = fmaf(v1[j + 0], wA.w, s);
                s = fmaf(v1[j + 1], wB.x, s);
                s = fmaf(v1[j + 2], wB.y, s);
                s = fmaf(v2[j + 0], wB.z, s);
                s = fmaf(v2[j + 1], wB.w, s);
                s = fmaf(v2[j + 2], wC,   s);
                acc[o * 4 + j] = s;
            }
        }
    }

    float* ob = out + (size_t)b * OUTC * HWSZ + p0;
    #pragma unroll
    for (int o = 0; o < OUTC; ++o) {
        float4 r;
        r.x = acc[o * 4 + 0]; r.y = acc[o * 4 + 1];
        r.z = acc[o * 4 + 2]; r.w = acc[o * 4 + 3];
        *(float4*)(ob + (size_t)o * HWSZ) = r;
    }
}

// ---------------------------------------------------------------------------
extern "C" void kernel_launch(void* const* d_in, const int* in_sizes, int n_in,
                              void* d_out, int out_size, void* d_ws, size_t ws_size,
                              hipStream_t stream) {
    const float* x      = (const float*)d_in[0];
    const float* w1     = (const float*)d_in[1];
    const float* w2     = (const float*)d_in[2];
    const float* b2     = (const float*)d_in[3];
    const float* weight = (const float*)d_in[4];
    float* out = (float*)d_out;

    float* pooled = (float*)d_ws;            // 256 floats
    float* wmix   = (float*)d_ws + 256;      // 16*3072 floats (~197 KB total)

    dg_pool_kernel<<<BB * CIN, 256, 0, stream>>>(x, pooled);
    dg_mix_kernel<<<BB, 64, 0, stream>>>(pooled, w1, w2, b2, weight, wmix);
    dg_conv_kernel<<<dim3(HWSZ / 1024, BB), 256, 0, stream>>>(x, wmix, out);
}

// Round 2
// 250.832 us; speedup vs baseline: 1.1986x; 1.1986x over previous
//
#include <hip/hip_runtime.h>
#include <hip/hip_bf16.h>
#include <math.h>

// Problem constants
#define BB   16
#define CIN  16
#define HH   320
#define WW   320
#define OUTC 16
#define KK   4
#define HID  5
#define HWSZ (HH * WW)        // 102400

// Conv tiling
#define TW   64               // tile width (pixels)
#define TH   16               // tile height (rows)
#define LROW 68               // LDS row stride in pixels (66 needed, 68 for quads)
#define LROWS 18              // TH + 2 halo
#define LDSN (LROWS * LROW * CIN)   // shorts: 19584 (39168 B)
#define KCH  5                // K chunks of 32 (K = 144 padded to 160)

typedef __attribute__((ext_vector_type(8))) short bf16x8_t;
typedef __attribute__((ext_vector_type(4))) float f32x4_t;

static __device__ __forceinline__ unsigned short f2bf(float f) {
    union { float f; unsigned u; } x; x.f = f;
    unsigned r = x.u + 0x7FFF + ((x.u >> 16) & 1);   // round-to-nearest-even
    return (unsigned short)(r >> 16);
}

// ---------------------------------------------------------------------------
// Kernel 1: global average pool. One block per (b,c) plane, 1024 threads.
// ---------------------------------------------------------------------------
__global__ __launch_bounds__(1024)
void dg_pool_kernel(const float* __restrict__ x, float* __restrict__ pooled) {
    const int plane = blockIdx.x;              // b*CIN + c, 0..255
    const float4* p4 = (const float4*)(x + (size_t)plane * HWSZ);
    float s = 0.f;
    #pragma unroll 5
    for (int i = threadIdx.x; i < HWSZ / 4; i += 1024) {
        float4 v = p4[i];
        s += (v.x + v.y) + (v.z + v.w);
    }
    #pragma unroll
    for (int off = 32; off > 0; off >>= 1) s += __shfl_down(s, off, 64);
    __shared__ float red[16];
    if ((threadIdx.x & 63) == 0) red[threadIdx.x >> 6] = s;
    __syncthreads();
    if (threadIdx.x == 0) {
        float t = 0.f;
        #pragma unroll
        for (int i = 0; i < 16; ++i) t += red[i];
        pooled[plane] = t * (1.f / (float)HWSZ);
    }
}

// ---------------------------------------------------------------------------
// Kernel 2: attention MLP + scrambled softmax + expert mix, emitted directly
// in MFMA B-fragment lane order (bf16), K padded 144->160 with zeros.
// wB[b][kc][lane][j] : B[k = kc*32 + (lane>>4)*8 + j][n = lane&15]
//                    = wmix[o=n][c = k&15][tap = k>>4]
// One block per batch sample, 64 threads.
// ---------------------------------------------------------------------------
__global__ __launch_bounds__(64)
void dg_mix_kernel(const float* __restrict__ pooled,
                   const float* __restrict__ w1,
                   const float* __restrict__ w2,
                   const float* __restrict__ b2,
                   const float* __restrict__ weight,
                   unsigned short* __restrict__ wB) {
    const int b = blockIdx.x;
    const int tid = threadIdx.x;   // 0..63
    __shared__ float sm[64];
    __shared__ float coeff[64];    // flat softmax, (k*16+o) order

    float pb[CIN];
    #pragma unroll
    for (int c = 0; c < CIN; ++c) pb[c] = pooled[b * CIN + c];
    float hid[HID];
    #pragma unroll
    for (int h = 0; h < HID; ++h) {
        float a = 0.f;
        #pragma unroll
        for (int c = 0; c < CIN; ++c) a = fmaf(pb[c], w1[h * CIN + c], a);
        hid[h] = fmaxf(a, 0.f);
    }
    float a = b2[tid];
    #pragma unroll
    for (int h = 0; h < HID; ++h) a = fmaf(hid[h], w2[tid * HID + h], a);
    sm[tid] = a;
    __syncthreads();

    const int oa = tid & 15;
    float a0 = sm[oa], a1 = sm[16 + oa], a2 = sm[32 + oa], a3 = sm[48 + oa];
    float m = fmaxf(fmaxf(a0, a1), fmaxf(a2, a3));
    float denom = expf(a0 - m) + expf(a1 - m) + expf(a2 - m) + expf(a3 - m);
    coeff[tid] = expf(sm[tid] - m) / denom;
    __syncthreads();

    const int o = tid & 15;
    const int kbase = (tid >> 4) * 8;
    #pragma unroll
    for (int kc = 0; kc < KCH; ++kc) {
        unsigned short frag[8];
        #pragma unroll
        for (int j = 0; j < 8; ++j) {
            const int k = kc * 32 + kbase + j;
            float v = 0.f;
            if (k < 144) {
                const int tap = k >> 4;
                const int c = k & 15;
                const float* wp = weight + (((size_t)(o * CIN + c) * 9 + tap) << 2);
                v = coeff[o * 4 + 0] * wp[0] + coeff[o * 4 + 1] * wp[1]
                  + coeff[o * 4 + 2] * wp[2] + coeff[o * 4 + 3] * wp[3];
            }
            frag[j] = f2bf(v);
        }
        unsigned short* dst = wB + (((size_t)(b * KCH + kc) * 64) + tid) * 8;
        #pragma unroll
        for (int j = 0; j < 8; ++j) dst[j] = frag[j];
    }
}

// ---------------------------------------------------------------------------
// Kernel 3: implicit-GEMM conv via mfma_f32_16x16x32_bf16.
// Block = 256 thr (4 waves), tile = 64x16 pixels, per-b.
// LDS: x tile as bf16, [pixel][16ch] = 32 B/pixel, 16-B halves XOR-swizzled
// by pixel parity to break bank aliasing.
// Wave w handles rows 4w..4w+3; M-tile = 16 consecutive pixels in a row.
// ---------------------------------------------------------------------------
__global__ __launch_bounds__(256, 2)
void dg_conv_kernel(const float* __restrict__ x,
                    const unsigned short* __restrict__ wB,
                    float* __restrict__ out) {
    const int b   = blockIdx.z;
    const int by0 = blockIdx.y * TH;
    const int bx0 = blockIdx.x * TW;
    const int tid = threadIdx.x;
    const int lane = tid & 63;
    const int wave = tid >> 6;

    __shared__ __align__(16) unsigned short sx[LDSN];

    // ---- B fragments (per-lane, coalesced 16-B global loads; L2-resident) ----
    bf16x8_t Bf[KCH];
    {
        const unsigned short* wBb = wB + (size_t)b * KCH * 512;
        #pragma unroll
        for (int kc = 0; kc < KCH; ++kc)
            Bf[kc] = *(const bf16x8_t*)(wBb + kc * 512 + lane * 8);
    }

    // ---- stage x tile -> LDS (bf16) ----
    // tasks: cp (8 channel-pairs) x row (18) x qx (17 quads of 4 px), qx fastest
    {
        const float* xb = x + (size_t)b * CIN * HWSZ;
        #pragma unroll 1
        for (int it = 0; it < 10; ++it) {
            const int t = tid + it * 256;
            if (t < 8 * LROWS * 17) {
                const int qx  = t % 17;
                const int t2  = t / 17;
                const int row = t2 % LROWS;
                const int cp  = t2 / LROWS;
                const int gy  = by0 - 1 + row;
                const bool vy = ((unsigned)gy < HH);
                const float* xr0 = xb + (size_t)(2 * cp) * HWSZ + (size_t)gy * WW;
                #pragma unroll
                for (int j = 0; j < 4; ++j) {
                    const int xx = qx * 4 + j;
                    const int gx = bx0 - 1 + xx;
                    const bool v = vy && ((unsigned)gx < WW);
                    const float v0 = v ? xr0[gx] : 0.f;
                    const float v1 = v ? xr0[HWSZ + gx] : 0.f;
                    const unsigned packed =
                        (unsigned)f2bf(v0) | ((unsigned)f2bf(v1) << 16);
                    const int P = row * LROW + xx;
                    const int idx = P * 16 + (((cp >> 2) ^ (P & 1)) << 3) + (cp & 3) * 2;
                    *(unsigned*)&sx[idx] = packed;
                }
            }
        }
    }

    // ---- per-lane A-fragment addressing constants ----
    const int m     = lane & 15;          // pixel-in-tile / out pixel row of D? (m = M index)
    const int quad  = lane >> 4;
    const int chalf = quad & 1;
    int dP[KCH];
    #pragma unroll
    for (int kc = 0; kc < KCH; ++kc) {
        int t = 2 * kc + (quad >> 1);
        if (t > 8) t = 8;                 // k>=144: B is zero, clamp tap to stay in tile
        dP[kc] = (t / 3 - 1) * LROW + (t % 3 - 1);
    }

    f32x4_t acc[16];
    #pragma unroll
    for (int i = 0; i < 16; ++i) acc[i] = (f32x4_t){0.f, 0.f, 0.f, 0.f};

    __syncthreads();

    // ---- main MFMA loop: 4 rows x 4 x-tiles x 5 K-chunks ----
    #pragma unroll
    for (int rr = 0; rr < 4; ++rr) {
        #pragma unroll
        for (int tx = 0; tx < 4; ++tx) {
            const int P0 = (4 * wave + rr + 1) * LROW + 1 + tx * 16 + m;
            #pragma unroll
            for (int kc = 0; kc < KCH; ++kc) {
                const int P = P0 + dP[kc];
                const int idx = P * 16 + ((chalf ^ (P & 1)) << 3);
                const bf16x8_t Af = *(const bf16x8_t*)&sx[idx];
                acc[rr * 4 + tx] = __builtin_amdgcn_mfma_f32_16x16x32_bf16(
                    Af, Bf[kc], acc[rr * 4 + tx], 0, 0, 0);
            }
        }
    }

    // ---- epilogue: D layout col=lane&15=outc n, row=quad*4+reg=pixel ----
    const int n = lane & 15;
    float* ob = out + ((size_t)(b * OUTC + n)) * HWSZ;
    #pragma unroll
    for (int rr = 0; rr < 4; ++rr) {
        const int gy = by0 + 4 * wave + rr;
        #pragma unroll
        for (int tx = 0; tx < 4; ++tx) {
            const int gx = bx0 + tx * 16 + quad * 4;
            *(f32x4_t*)(ob + (size_t)gy * WW + gx) = acc[rr * 4 + tx];
        }
    }
}

// ---------------------------------------------------------------------------
extern "C" void kernel_launch(void* const* d_in, const int* in_sizes, int n_in,
                              void* d_out, int out_size, void* d_ws, size_t ws_size,
                              hipStream_t stream) {
    const float* x      = (const float*)d_in[0];
    const float* w1     = (const float*)d_in[1];
    const float* w2     = (const float*)d_in[2];
    const float* b2     = (const float*)d_in[3];
    const float* weight = (const float*)d_in[4];
    float* out = (float*)d_out;

    float* pooled = (float*)d_ws;                       // 256 floats
    unsigned short* wBf = (unsigned short*)((float*)d_ws + 256);  // 16*5*64*8 bf16 = 80 KB

    dg_pool_kernel<<<BB * CIN, 1024, 0, stream>>>(x, pooled);
    dg_mix_kernel<<<BB, 64, 0, stream>>>(pooled, w1, w2, b2, weight, wBf);
    dg_conv_kernel<<<dim3(WW / TW, HH / TH, BB), 256, 0, stream>>>(x, wBf, out);
}

// Round 3
// 242.484 us; speedup vs baseline: 1.2398x; 1.0344x over previous
//
#include <hip/hip_runtime.h>
#include <hip/hip_bf16.h>
#include <math.h>

// Problem constants
#define BB   16
#define CIN  16
#define HH   320
#define WW   320
#define OUTC 16
#define KK   4
#define HID  5
#define HWSZ (HH * WW)        // 102400

// Conv tiling
#define TW   64               // tile width (pixels)
#define TH   16               // tile height (rows)
#define LROW 66               // LDS row width in pixels (64 + 2 halo)
#define LROWS 18              // TH + 2 halo
#define NPIX (LROWS * LROW)   // 1188 pixels per tile
#define NTASK (2 * NPIX)      // 2376 staging tasks (pixel x channel-half)
#define LDSN (2 * NPIX * 8)   // shorts: 19008 (38016 B)
#define KCH  5                // K chunks of 32 (K = 144 padded to 160)

typedef __attribute__((ext_vector_type(8))) short bf16x8_t;
typedef __attribute__((ext_vector_type(4))) float f32x4_t;

static __device__ __forceinline__ unsigned short f2bf(float f) {
    union { float f; unsigned u; } x; x.f = f;
    unsigned r = x.u + 0x7FFF + ((x.u >> 16) & 1);   // round-to-nearest-even
    return (unsigned short)(r >> 16);
}

// ---------------------------------------------------------------------------
// Kernel 1: global average pool. One block per (b,c) plane, 1024 threads.
// ---------------------------------------------------------------------------
__global__ __launch_bounds__(1024)
void dg_pool_kernel(const float* __restrict__ x, float* __restrict__ pooled) {
    const int plane = blockIdx.x;              // b*CIN + c, 0..255
    const float4* p4 = (const float4*)(x + (size_t)plane * HWSZ);
    float s = 0.f;
    #pragma unroll 5
    for (int i = threadIdx.x; i < HWSZ / 4; i += 1024) {
        float4 v = p4[i];
        s += (v.x + v.y) + (v.z + v.w);
    }
    #pragma unroll
    for (int off = 32; off > 0; off >>= 1) s += __shfl_down(s, off, 64);
    __shared__ float red[16];
    if ((threadIdx.x & 63) == 0) red[threadIdx.x >> 6] = s;
    __syncthreads();
    if (threadIdx.x == 0) {
        float t = 0.f;
        #pragma unroll
        for (int i = 0; i < 16; ++i) t += red[i];
        pooled[plane] = t * (1.f / (float)HWSZ);
    }
}

// ---------------------------------------------------------------------------
// Kernel 2: attention MLP + scrambled softmax + expert mix, emitted directly
// in MFMA B-fragment lane order (bf16), K padded 144->160 with zeros.
// wB[b][kc][lane][j] : B[k = kc*32 + (lane>>4)*8 + j][n = lane&15]
//                    = wmix[o=n][c = k&15][tap = k>>4]
// One block per batch sample, 64 threads.
// ---------------------------------------------------------------------------
__global__ __launch_bounds__(64)
void dg_mix_kernel(const float* __restrict__ pooled,
                   const float* __restrict__ w1,
                   const float* __restrict__ w2,
                   const float* __restrict__ b2,
                   const float* __restrict__ weight,
                   unsigned short* __restrict__ wB) {
    const int b = blockIdx.x;
    const int tid = threadIdx.x;   // 0..63
    __shared__ float sm[64];
    __shared__ float coeff[64];    // flat softmax, (k*16+o) order

    float pb[CIN];
    #pragma unroll
    for (int c = 0; c < CIN; ++c) pb[c] = pooled[b * CIN + c];
    float hid[HID];
    #pragma unroll
    for (int h = 0; h < HID; ++h) {
        float a = 0.f;
        #pragma unroll
        for (int c = 0; c < CIN; ++c) a = fmaf(pb[c], w1[h * CIN + c], a);
        hid[h] = fmaxf(a, 0.f);
    }
    float a = b2[tid];
    #pragma unroll
    for (int h = 0; h < HID; ++h) a = fmaf(hid[h], w2[tid * HID + h], a);
    sm[tid] = a;
    __syncthreads();

    const int oa = tid & 15;
    float a0 = sm[oa], a1 = sm[16 + oa], a2 = sm[32 + oa], a3 = sm[48 + oa];
    float m = fmaxf(fmaxf(a0, a1), fmaxf(a2, a3));
    float denom = expf(a0 - m) + expf(a1 - m) + expf(a2 - m) + expf(a3 - m);
    coeff[tid] = expf(sm[tid] - m) / denom;
    __syncthreads();

    const int o = tid & 15;
    const int kbase = (tid >> 4) * 8;
    #pragma unroll
    for (int kc = 0; kc < KCH; ++kc) {
        unsigned short frag[8];
        #pragma unroll
        for (int j = 0; j < 8; ++j) {
            const int k = kc * 32 + kbase + j;
            float v = 0.f;
            if (k < 144) {
                const int tap = k >> 4;
                const int c = k & 15;
                const float* wp = weight + (((size_t)(o * CIN + c) * 9 + tap) << 2);
                v = coeff[o * 4 + 0] * wp[0] + coeff[o * 4 + 1] * wp[1]
                  + coeff[o * 4 + 2] * wp[2] + coeff[o * 4 + 3] * wp[3];
            }
            frag[j] = f2bf(v);
        }
        unsigned short* dst = wB + (((size_t)(b * KCH + kc) * 64) + tid) * 8;
        #pragma unroll
        for (int j = 0; j < 8; ++j) dst[j] = frag[j];
    }
}

// ---------------------------------------------------------------------------
// Kernel 3: implicit-GEMM conv via mfma_f32_16x16x32_bf16.
// Block = 256 thr (4 waves), tile = 64x16 pixels, per-b.
// LDS layout: [chalf][pixel][8ch] bf16 -> 16-B slot index S = chalf*NPIX + P.
// Staging task order == layout order => ds_write_b128 with consecutive lanes
// on consecutive slots (conflict-free). A-reads: consecutive pixels ->
// consecutive slots (conflict-free).
// ---------------------------------------------------------------------------
__global__ __launch_bounds__(256, 4)
void dg_conv_kernel(const float* __restrict__ x,
                    const unsigned short* __restrict__ wB,
                    float* __restrict__ out) {
    const int b   = blockIdx.z;
    const int by0 = blockIdx.y * TH;
    const int bx0 = blockIdx.x * TW;
    const int tid = threadIdx.x;
    const int lane = tid & 63;
    const int wave = tid >> 6;

    __shared__ __align__(16) unsigned short sx[LDSN];

    // ---- B fragments (per-lane, coalesced 16-B global loads; L2-resident) ----
    bf16x8_t Bf[KCH];
    {
        const unsigned short* wBb = wB + (size_t)b * KCH * 512;
        #pragma unroll
        for (int kc = 0; kc < KCH; ++kc)
            Bf[kc] = *(const bf16x8_t*)(wBb + kc * 512 + lane * 8);
    }

    // ---- stage x tile -> LDS (bf16), conflict-free writes ----
    {
        const float* xb = x + (size_t)b * CIN * HWSZ;
        #pragma unroll 1
        for (int it = 0; it < 10; ++it) {
            const int t = tid + it * 256;
            if (t < NTASK) {
                const int half = (t >= NPIX) ? 1 : 0;
                const int P    = t - half * NPIX;
                const int row  = P / LROW;
                const int px   = P - row * LROW;
                const int gy = by0 - 1 + row;
                const int gx = bx0 - 1 + px;
                const bool valid = ((unsigned)gy < HH) && ((unsigned)gx < WW);
                const int gyc = valid ? gy : 0;
                const int gxc = valid ? gx : 0;
                const float* bp = xb + (size_t)(half * 8) * HWSZ
                                     + (size_t)gyc * WW + gxc;
                bf16x8_t v8;
                #pragma unroll
                for (int j = 0; j < 8; ++j) {
                    float v = valid ? bp[(size_t)j * HWSZ] : 0.f;
                    v8[j] = (short)f2bf(v);
                }
                *(bf16x8_t*)&sx[(size_t)t * 8] = v8;
            }
        }
    }

    // ---- per-lane A-fragment addressing constants ----
    const int m     = lane & 15;
    const int quad  = lane >> 4;
    const int chalf = quad & 1;
    int dP[KCH];
    #pragma unroll
    for (int kc = 0; kc < KCH; ++kc) {
        int t = 2 * kc + (quad >> 1);
        if (t > 8) t = 8;                 // k>=144: B is zero, clamp tap to stay in tile
        dP[kc] = (t / 3 - 1) * LROW + (t % 3 - 1);
    }
    const int hofs = chalf * NPIX;        // slot offset for channel half

    f32x4_t acc[16];
    #pragma unroll
    for (int i = 0; i < 16; ++i) acc[i] = (f32x4_t){0.f, 0.f, 0.f, 0.f};

    __syncthreads();

    // ---- main MFMA loop: 4 rows x 4 x-tiles x 5 K-chunks ----
    #pragma unroll
    for (int rr = 0; rr < 4; ++rr) {
        #pragma unroll
        for (int tx = 0; tx < 4; ++tx) {
            const int P0 = (4 * wave + rr + 1) * LROW + 1 + tx * 16 + m;
            #pragma unroll
            for (int kc = 0; kc < KCH; ++kc) {
                const int S = hofs + P0 + dP[kc];
                const bf16x8_t Af = *(const bf16x8_t*)&sx[(size_t)S * 8];
                acc[rr * 4 + tx] = __builtin_amdgcn_mfma_f32_16x16x32_bf16(
                    Af, Bf[kc], acc[rr * 4 + tx], 0, 0, 0);
            }
        }
    }

    // ---- epilogue: D layout col=lane&15=outc n, row=quad*4+reg=pixel ----
    const int n = lane & 15;
    float* ob = out + ((size_t)(b * OUTC + n)) * HWSZ;
    #pragma unroll
    for (int rr = 0; rr < 4; ++rr) {
        const int gy = by0 + 4 * wave + rr;
        #pragma unroll
        for (int tx = 0; tx < 4; ++tx) {
            const int gx = bx0 + tx * 16 + quad * 4;
            *(f32x4_t*)(ob + (size_t)gy * WW + gx) = acc[rr * 4 + tx];
        }
    }
}

// ---------------------------------------------------------------------------
extern "C" void kernel_launch(void* const* d_in, const int* in_sizes, int n_in,
                              void* d_out, int out_size, void* d_ws, size_t ws_size,
                              hipStream_t stream) {
    const float* x      = (const float*)d_in[0];
    const float* w1     = (const float*)d_in[1];
    const float* w2     = (const float*)d_in[2];
    const float* b2     = (const float*)d_in[3];
    const float* weight = (const float*)d_in[4];
    float* out = (float*)d_out;

    float* pooled = (float*)d_ws;                       // 256 floats
    unsigned short* wBf = (unsigned short*)((float*)d_ws + 256);  // 16*5*64*8 bf16 = 80 KB

    dg_pool_kernel<<<BB * CIN, 1024, 0, stream>>>(x, pooled);
    dg_mix_kernel<<<BB, 64, 0, stream>>>(pooled, w1, w2, b2, weight, wBf);
    dg_conv_kernel<<<dim3(WW / TW, HH / TH, BB), 256, 0, stream>>>(x, wBf, out);
}